// Round 5
// baseline (3751.889 us; speedup 1.0000x reference)
//
#include <hip/hip_runtime.h>

// ---------------------------------------------------------------------------
// VoxelSetAbstraction forward (PV-RCNN style) for MI355X
//   B=2, N_RAW=16384, N_KP=2048, M_VOX=8192, C_VOX=64
//   BEV: (2,256,200,176), stride 8, voxel 0.05, pc_min (0,-40,-3)
//   raw SA: radii (0.4,0.8) ns (16,16), MLP 4->16->16
//   conv SA: radii (1.2,2.4) ns (16,32), MLP 67->64->64
//   fusion: 416 -> 128
// ---------------------------------------------------------------------------

#define NRAW   16384
#define MVOX   8192
#define NKP    2048
#define NKPALL 4096   // B * NKP

typedef float v2f __attribute__((ext_vector_type(2)));

__device__ __constant__ float kBNS = (float)0.9999950000374997; // 1/sqrt(1+1e-5)

// VOP3P packed f32 (gfx90a+): bit-identical IEEE per-element add/mul, 2/instr.
// The HIP compiler does not form these from ext_vector f32 math (round-4 PMC
// showed scalar issue counts), so force them. "v" constraints also pin the
// point/dist arrays into arch VGPRs.
__device__ __forceinline__ v2f pk_add(v2f a, v2f b) {
  v2f d; asm("v_pk_add_f32 %0, %1, %2" : "=v"(d) : "v"(a), "v"(b)); return d;
}
__device__ __forceinline__ v2f pk_mul(v2f a, v2f b) {
  v2f d; asm("v_pk_mul_f32 %0, %1, %2" : "=v"(d) : "v"(a), "v"(b)); return d;
}

// ---------------------------------------------------------------------------
// K0: pack points to interleaved float4 (x,y,z,intensity) + voxel centers
// ---------------------------------------------------------------------------
__global__ __launch_bounds__(256) void prep_kernel(
    const float* __restrict__ pts, const int* __restrict__ vc,
    float4* __restrict__ xyz4, float4* __restrict__ cxyz4) {
#pragma clang fp contract(off)
  int i = blockIdx.x * 256 + threadIdx.x;
  if (i < 2 * NRAW) {
    const float* p = pts + (size_t)i * 5;
    xyz4[i] = make_float4(p[1], p[2], p[3], p[4]);
  }
  if (i < 2 * MVOX) {
    const int* v = vc + (size_t)i * 4;
    cxyz4[i] = make_float4(((float)v[3] + 0.5f) * 0.2f + 0.0f,
                           ((float)v[2] + 0.5f) * 0.2f + -40.0f,
                           ((float)v[1] + 0.5f) * 0.4f + -3.0f, 0.f);
  }
}

// ---------------------------------------------------------------------------
// Wave-wide u32 max via DPP (VALU pipe, zero DS). Lane 63 holds the result.
// ---------------------------------------------------------------------------
__device__ __forceinline__ unsigned wave_umax63(unsigned v) {
  unsigned t;
  t = (unsigned)__builtin_amdgcn_update_dpp(0, (int)v, 0xB1,  0xf, 0xf, true); v = v > t ? v : t;
  t = (unsigned)__builtin_amdgcn_update_dpp(0, (int)v, 0x4E,  0xf, 0xf, true); v = v > t ? v : t;
  t = (unsigned)__builtin_amdgcn_update_dpp(0, (int)v, 0x124, 0xf, 0xf, true); v = v > t ? v : t;
  t = (unsigned)__builtin_amdgcn_update_dpp(0, (int)v, 0x128, 0xf, 0xf, true); v = v > t ? v : t;
  t = (unsigned)__builtin_amdgcn_update_dpp(0, (int)v, 0x142, 0xa, 0xf, true); v = v > t ? v : t;
  t = (unsigned)__builtin_amdgcn_update_dpp(0, (int)v, 0x143, 0xc, 0xf, true); v = v > t ? v : t;
  return v;  // valid in lane 63
}

// ---------------------------------------------------------------------------
// K1: farthest point sampling. One block/batch, 512 thr, 32 pts/thread as
// 16 float2 pairs (pair jj: .x = pt jj*512+t, .y = pt jj*512+t+8192), all
// arithmetic via forced v_pk_* (exact numpy order: sub = add of negated
// center; sum ((dx^2+dy^2)+dz^2); fmin scalar).
// Per iter: dist update -> pk/scalar fmax tree -> bv; DPP wave max ->
// lane63 ds_atomic_max(slot_v); B1; broadcast-read gmax; winning lanes only
// (s_cbranch_execz skips 7/8 waves) scan regs for first index ->
// ds_atomic_min(slot_i); B2; readfirstlane -> one s_load_dwordx4 of winner
// coords. First-index tiebreak exact at every level.
// ---------------------------------------------------------------------------
__global__ __launch_bounds__(512, 2) void fps_kernel(
    const float4* __restrict__ xyz4,
    float* __restrict__ kx, float* __restrict__ ky, float* __restrict__ kz) {
#pragma clang fp contract(off)
  const int b = blockIdx.x;
  const int t = threadIdx.x;
  const float4* bp = xyz4 + b * NRAW;

  v2f px2[16], py2[16], pz2[16], dd2[16];
#pragma unroll
  for (int jj = 0; jj < 16; ++jj) {
    const float4 a = bp[jj * 512 + t];
    const float4 c = bp[jj * 512 + t + 8192];
    px2[jj] = (v2f){a.x, c.x};
    py2[jj] = (v2f){a.y, c.y};
    pz2[jj] = (v2f){a.z, c.z};
    dd2[jj] = (v2f){1e10f, 1e10f};
  }

  const float4 p0 = bp[0];
  float lx = p0.x, ly = p0.y, lz = p0.z;
  if (t == 0) { kx[b * NKP] = lx; ky[b * NKP] = ly; kz[b * NKP] = lz; }

  __shared__ unsigned slot_v[2];   // atomicMax'd block max value bits
  __shared__ unsigned slot_i[2];   // atomicMin'd winner index
  if (t < 2) { slot_v[t] = 0u; slot_i[t] = 0xFFFFFFFFu; }
  __syncthreads();

  for (int s = 1; s < NKP; ++s) {
    const int buf = s & 1;
    const v2f nlx = (v2f){-lx, -lx}, nly = (v2f){-ly, -ly}, nlz = (v2f){-lz, -lz};
#pragma unroll
    for (int jj = 0; jj < 16; ++jj) {
      v2f dx = pk_add(px2[jj], nlx);
      v2f dy = pk_add(py2[jj], nly);
      v2f dz = pk_add(pz2[jj], nlz);
      v2f d2 = pk_add(pk_add(pk_mul(dx, dx), pk_mul(dy, dy)), pk_mul(dz, dz));
      dd2[jj].x = fminf(dd2[jj].x, d2.x);
      dd2[jj].y = fminf(dd2[jj].y, d2.y);
    }
    // max tree over the 32 residual distances
    float m0 = fmaxf(fmaxf(dd2[0].x, dd2[0].y), fmaxf(dd2[1].x, dd2[1].y));
    float m1 = fmaxf(fmaxf(dd2[2].x, dd2[2].y), fmaxf(dd2[3].x, dd2[3].y));
    float m2 = fmaxf(fmaxf(dd2[4].x, dd2[4].y), fmaxf(dd2[5].x, dd2[5].y));
    float m3 = fmaxf(fmaxf(dd2[6].x, dd2[6].y), fmaxf(dd2[7].x, dd2[7].y));
    float m4 = fmaxf(fmaxf(dd2[8].x, dd2[8].y), fmaxf(dd2[9].x, dd2[9].y));
    float m5 = fmaxf(fmaxf(dd2[10].x, dd2[10].y), fmaxf(dd2[11].x, dd2[11].y));
    float m6 = fmaxf(fmaxf(dd2[12].x, dd2[12].y), fmaxf(dd2[13].x, dd2[13].y));
    float m7 = fmaxf(fmaxf(dd2[14].x, dd2[14].y), fmaxf(dd2[15].x, dd2[15].y));
    const float bv = fmaxf(fmaxf(fmaxf(m0, m1), fmaxf(m2, m3)),
                           fmaxf(fmaxf(m4, m5), fmaxf(m6, m7)));

    const unsigned vb = __float_as_uint(bv);
    const unsigned wm = wave_umax63(vb);
    if ((t & 63) == 63) atomicMax(&slot_v[buf], wm);
    __syncthreads();                              // B1

    const unsigned gmax = slot_v[buf];            // broadcast LDS read
    if (t == 0) slot_v[1 - buf] = 0u;             // reset for next iter (B2 orders)
    if (vb == gmax) {                             // winning lane(s) only
      int bi = 0;
#pragma unroll
      for (int jj = 15; jj >= 0; --jj)            // hi half (idx jj*512+t+8192)
        if (__float_as_uint(dd2[jj].y) == gmax) bi = jj * 512 + t + 8192;
#pragma unroll
      for (int jj = 15; jj >= 0; --jj)            // lo half wins ties
        if (__float_as_uint(dd2[jj].x) == gmax) bi = jj * 512 + t;
      atomicMin(&slot_i[buf], (unsigned)bi);
    }
    __syncthreads();                              // B2

    const int wi = __builtin_amdgcn_readfirstlane((int)slot_i[buf]);
    if (t == 0) slot_i[1 - buf] = 0xFFFFFFFFu;    // reset (B1 of s+1 orders)
    const float4 c = bp[wi];                      // uniform -> s_load_dwordx4
    lx = c.x; ly = c.y; lz = c.z;
    if (t == 0) { kx[b * NKP + s] = lx; ky[b * NKP + s] = ly; kz[b * NKP + s] = lz; }
  }
}

// ---------------------------------------------------------------------------
// K2: BEV bilinear. one block per keypoint, 256 threads = 256 channels.
// ---------------------------------------------------------------------------
__global__ __launch_bounds__(256) void bev_kernel(
    const float* __restrict__ sf, const float* __restrict__ kx,
    const float* __restrict__ ky, float* __restrict__ feats) {
#pragma clang fp contract(off)
  const int kidx = blockIdx.x;
  const int c = threadIdx.x;
  const int b = kidx >> 11;
  const float x = (kx[kidx] - 0.0f) / 0.05f / 8.0f;
  const float y = (ky[kidx] - (-40.0f)) / 0.05f / 8.0f;
  const float xf = floorf(x), yf = floorf(y);
  int x0 = (int)xf;     x0 = x0 < 0 ? 0 : (x0 > 175 ? 175 : x0);
  int x1 = (int)xf + 1; x1 = x1 < 0 ? 0 : (x1 > 175 ? 175 : x1);
  int y0 = (int)yf;     y0 = y0 < 0 ? 0 : (y0 > 199 ? 199 : y0);
  int y1 = (int)yf + 1; y1 = y1 < 0 ? 0 : (y1 > 199 ? 199 : y1);
  const float x0f = (float)x0, x1f = (float)x1, y0f = (float)y0, y1f = (float)y1;
  const float wa = (x - x0f) * (y1f - y);
  const float wb = (x1f - x) * (y1f - y);
  const float wc = (x1f - x) * (y - y0f);
  const float wd = (x - x0f) * (y - y0f);
  const float* base = sf + ((size_t)b * 256 + c) * (200 * 176);
  const float fa = base[y1 * 176 + x0];
  const float fb = base[y1 * 176 + x1];
  const float fc = base[y0 * 176 + x1];
  const float fd = base[y0 * 176 + x0];
  float r = fd * wb; r = r + fc * wa; r = r + fa * wc; r = r + fb * wd;
  feats[(size_t)kidx * 416 + c] = r;
}

// ---------------------------------------------------------------------------
// K3: raw SA. one wave per (keypoint, radius). MLP 4->16->16, max-pool.
// ---------------------------------------------------------------------------
__global__ __launch_bounds__(256) void raw_sa_kernel(
    const float4* __restrict__ xyz4,
    const float* __restrict__ kx, const float* __restrict__ ky,
    const float* __restrict__ kz,
    const float* __restrict__ w0, const float* __restrict__ g0,
    const float* __restrict__ b0, const float* __restrict__ w1,
    const float* __restrict__ g1, const float* __restrict__ b1,
    float* __restrict__ feats) {
  const int wv = threadIdx.x >> 6;
  const int lane = threadIdx.x & 63;
  const int gw = blockIdx.x * 4 + wv;       // 0..8191
  const int ri = gw >> 12;                  // radius index 0/1
  const int kidx = gw & 4095;
  const int b = kidx >> 11;
  const float R2 = ri ? (float)(0.8 * 0.8) : (float)(0.4 * 0.4);

  __shared__ int   idxl[4][16];
  __shared__ float hbuf[4][16][17];

  const float kxv = kx[kidx], kyv = ky[kidx], kzv = kz[kidx];
  const int base = b * NRAW;
  int cnt = 0;
  {
#pragma clang fp contract(off)
    for (int ch = 0; ch < NRAW / 64 && cnt < 16; ++ch) {
      const float4 q = xyz4[base + ch * 64 + lane];
      float dx = kxv - q.x, dy = kyv - q.y, dz = kzv - q.z;
      float d2 = dx * dx; d2 = d2 + dy * dy; d2 = d2 + dz * dz;
      unsigned long long m = __ballot(d2 < R2);
      while (m && cnt < 16) {
        int bit = __builtin_ctzll(m);
        if (lane == 0) idxl[wv][cnt] = ch * 64 + bit;
        ++cnt;
        m &= m - 1;
      }
    }
  }
  const int outoff = kidx * 416 + 256 + ri * 16;
  if (cnt == 0) {
    if (lane < 16) feats[outoff + lane] = 0.f;
    return;
  }
  __threadfence_block();

  const int s = lane & 15, cq = lane >> 4;
  const int ss = (s < cnt) ? s : 0;          // duplicate sample 0 (matches ref pad)
  const float4 q = xyz4[base + idxl[wv][ss]];
  const float gx = q.x - kxv, gy = q.y - kyv, gz = q.z - kzv, gi = q.w;
  const int wb0 = ri * 64, cb = ri * 16;
#pragma unroll
  for (int j = 0; j < 4; ++j) {
    int c = cq * 4 + j;
    float a = gx * w0[wb0 + c];
    a = fmaf(gy, w0[wb0 + 16 + c], a);
    a = fmaf(gz, w0[wb0 + 32 + c], a);
    a = fmaf(gi, w0[wb0 + 48 + c], a);
    a = fmaf(a, g0[cb + c] * kBNS, b0[cb + c]);
    hbuf[wv][s][c] = fmaxf(a, 0.f);
  }
  __threadfence_block();
  float o0 = 0.f, o1 = 0.f, o2 = 0.f, o3 = 0.f;
  const int wb1 = ri * 256;
#pragma unroll
  for (int k = 0; k < 16; ++k) {
    float hk = hbuf[wv][s][k];
    o0 = fmaf(hk, w1[wb1 + k * 16 + cq * 4 + 0], o0);
    o1 = fmaf(hk, w1[wb1 + k * 16 + cq * 4 + 1], o1);
    o2 = fmaf(hk, w1[wb1 + k * 16 + cq * 4 + 2], o2);
    o3 = fmaf(hk, w1[wb1 + k * 16 + cq * 4 + 3], o3);
  }
  float v0 = fmaxf(fmaf(o0, g1[cb + cq * 4 + 0] * kBNS, b1[cb + cq * 4 + 0]), 0.f);
  float v1 = fmaxf(fmaf(o1, g1[cb + cq * 4 + 1] * kBNS, b1[cb + cq * 4 + 1]), 0.f);
  float v2 = fmaxf(fmaf(o2, g1[cb + cq * 4 + 2] * kBNS, b1[cb + cq * 4 + 2]), 0.f);
  float v3 = fmaxf(fmaf(o3, g1[cb + cq * 4 + 3] * kBNS, b1[cb + cq * 4 + 3]), 0.f);
#pragma unroll
  for (int off = 1; off < 16; off <<= 1) {
    v0 = fmaxf(v0, __shfl_xor(v0, off, 64));
    v1 = fmaxf(v1, __shfl_xor(v1, off, 64));
    v2 = fmaxf(v2, __shfl_xor(v2, off, 64));
    v3 = fmaxf(v3, __shfl_xor(v3, off, 64));
  }
  if (s == 0) {
    feats[outoff + cq * 4 + 0] = v0;
    feats[outoff + cq * 4 + 1] = v1;
    feats[outoff + cq * 4 + 2] = v2;
    feats[outoff + cq * 4 + 3] = v3;
  }
}

// ---------------------------------------------------------------------------
// K4: conv SA. one wave per (keypoint, radius). MLP 67->64->64, max-pool.
// ---------------------------------------------------------------------------
__global__ __launch_bounds__(256) void conv_sa_kernel(
    const float4* __restrict__ cxyz4, const float* __restrict__ vf,
    const float* __restrict__ kx, const float* __restrict__ ky,
    const float* __restrict__ kz,
    const float* __restrict__ w0, const float* __restrict__ g0,
    const float* __restrict__ b0, const float* __restrict__ w1,
    const float* __restrict__ g1, const float* __restrict__ b1,
    float* __restrict__ feats) {
  const int wv = threadIdx.x >> 6;
  const int lane = threadIdx.x & 63;
  const int gw = blockIdx.x * 4 + wv;
  const int ri = gw >> 12;
  const int kidx = gw & 4095;
  const int b = kidx >> 11;
  const int NS = ri ? 32 : 16;
  const float R2 = ri ? (float)(2.4 * 2.4) : (float)(1.2 * 1.2);

  __shared__ int   idxl[4][32];
  __shared__ float gbuf[4][64];
  __shared__ float hbuf[4][32][64];

  const float kxv = kx[kidx], kyv = ky[kidx], kzv = kz[kidx];
  const int base = b * MVOX;
  int cnt = 0;
  {
#pragma clang fp contract(off)
    for (int ch = 0; ch < MVOX / 64 && cnt < NS; ++ch) {
      const float4 q = cxyz4[base + ch * 64 + lane];
      float dx = kxv - q.x, dy = kyv - q.y, dz = kzv - q.z;
      float d2 = dx * dx; d2 = d2 + dy * dy; d2 = d2 + dz * dz;
      unsigned long long m = __ballot(d2 < R2);
      while (m && cnt < NS) {
        int bit = __builtin_ctzll(m);
        if (lane == 0) idxl[wv][cnt] = ch * 64 + bit;
        ++cnt;
        m &= m - 1;
      }
    }
  }
  const int outoff = kidx * 416 + 288 + ri * 64;
  if (cnt == 0) {
    feats[outoff + lane] = 0.f;
    return;
  }
  __threadfence_block();

  // per-lane weight columns (lane == output channel)
  const float wA0 = w0[(ri * 67 + 0) * 64 + lane];
  const float wA1 = w0[(ri * 67 + 1) * 64 + lane];
  const float wA2 = w0[(ri * 67 + 2) * 64 + lane];
  float wB[64];
#pragma unroll
  for (int k = 0; k < 64; ++k) wB[k] = w0[(ri * 67 + 3 + k) * 64 + lane];
  float wC[64];
#pragma unroll
  for (int k = 0; k < 64; ++k) wC[k] = w1[(ri * 64 + k) * 64 + lane];
  const float s0 = g0[ri * 64 + lane] * kBNS, bb0 = b0[ri * 64 + lane];
  const float s1 = g1[ri * 64 + lane] * kBNS, bb1 = b1[ri * 64 + lane];

  for (int sm = 0; sm < cnt; ++sm) {
    const int p = base + idxl[wv][sm];
    const float4 q = cxyz4[p];
    const float ox = q.x - kxv, oy = q.y - kyv, oz = q.z - kzv;
    gbuf[wv][lane] = vf[(size_t)p * 64 + lane];
    __threadfence_block();
    float acc = ox * wA0;
    acc = fmaf(oy, wA1, acc);
    acc = fmaf(oz, wA2, acc);
#pragma unroll
    for (int k4 = 0; k4 < 16; ++k4) {
      float4 g4 = *(const float4*)&gbuf[wv][k4 * 4];
      acc = fmaf(g4.x, wB[k4 * 4 + 0], acc);
      acc = fmaf(g4.y, wB[k4 * 4 + 1], acc);
      acc = fmaf(g4.z, wB[k4 * 4 + 2], acc);
      acc = fmaf(g4.w, wB[k4 * 4 + 3], acc);
    }
    hbuf[wv][sm][lane] = fmaxf(fmaf(acc, s0, bb0), 0.f);
    __threadfence_block();
  }
  float mx = -1e30f;
  for (int sm = 0; sm < cnt; ++sm) {
    float acc = 0.f;
#pragma unroll
    for (int k4 = 0; k4 < 16; ++k4) {
      float4 h4 = *(const float4*)&hbuf[wv][sm][k4 * 4];
      acc = fmaf(h4.x, wC[k4 * 4 + 0], acc);
      acc = fmaf(h4.y, wC[k4 * 4 + 1], acc);
      acc = fmaf(h4.z, wC[k4 * 4 + 2], acc);
      acc = fmaf(h4.w, wC[k4 * 4 + 3], acc);
    }
    mx = fmaxf(mx, fmaxf(fmaf(acc, s1, bb1), 0.f));
  }
  feats[outoff + lane] = mx;
}

// ---------------------------------------------------------------------------
// K5: fusion 416 -> 128 + BN + ReLU. one thread per (kp, out-channel).
// ---------------------------------------------------------------------------
__global__ __launch_bounds__(256) void fusion_kernel(
    const float* __restrict__ feats, const float* __restrict__ fw,
    const float* __restrict__ fg, const float* __restrict__ fb,
    float* __restrict__ out) {
  const int gid = blockIdx.x * 256 + threadIdx.x;
  const int kidx = gid >> 7, c = gid & 127;
  const float* f = feats + (size_t)kidx * 416;
  float acc = 0.f;
#pragma unroll 4
  for (int k = 0; k < 416; k += 4) {
    float4 fv = *(const float4*)(f + k);
    acc = fmaf(fv.x, fw[(k + 0) * 128 + c], acc);
    acc = fmaf(fv.y, fw[(k + 1) * 128 + c], acc);
    acc = fmaf(fv.z, fw[(k + 2) * 128 + c], acc);
    acc = fmaf(fv.w, fw[(k + 3) * 128 + c], acc);
  }
  out[gid] = fmaxf(fmaf(acc, fg[c] * kBNS, fb[c]), 0.f);
}

// ---------------------------------------------------------------------------
extern "C" void kernel_launch(void* const* d_in, const int* in_sizes, int n_in,
                              void* d_out, int out_size, void* d_ws, size_t ws_size,
                              hipStream_t stream) {
  (void)in_sizes; (void)n_in; (void)out_size; (void)ws_size;
  const float* pts = (const float*)d_in[0];
  const float* sf  = (const float*)d_in[1];
  const int*   vc  = (const int*)d_in[2];
  const float* vf  = (const float*)d_in[3];
  const float* raw_w0 = (const float*)d_in[4];
  const float* raw_g0 = (const float*)d_in[5];
  const float* raw_b0 = (const float*)d_in[6];
  const float* raw_w1 = (const float*)d_in[7];
  const float* raw_g1 = (const float*)d_in[8];
  const float* raw_b1 = (const float*)d_in[9];
  const float* conv_w0 = (const float*)d_in[10];
  const float* conv_g0 = (const float*)d_in[11];
  const float* conv_b0 = (const float*)d_in[12];
  const float* conv_w1 = (const float*)d_in[13];
  const float* conv_g1 = (const float*)d_in[14];
  const float* conv_b1 = (const float*)d_in[15];
  const float* fus_w = (const float*)d_in[16];
  const float* fus_g = (const float*)d_in[17];
  const float* fus_b = (const float*)d_in[18];
  float* out = (float*)d_out;

  float* W = (float*)d_ws;
  float4* xyz4  = (float4*)W;             // 32768 float4 = 131072 floats
  float4* cxyz4 = (float4*)(W + 131072);  // 16384 float4 = 65536 floats
  float* kx    = W + 196608;              // 4096 each
  float* ky    = W + 200704;
  float* kz    = W + 204800;
  float* feats = W + 208896;              // 4096 * 416

  prep_kernel<<<128, 256, 0, stream>>>(pts, vc, xyz4, cxyz4);
  fps_kernel<<<2, 512, 0, stream>>>(xyz4, kx, ky, kz);
  bev_kernel<<<NKPALL, 256, 0, stream>>>(sf, kx, ky, feats);
  raw_sa_kernel<<<2048, 256, 0, stream>>>(xyz4, kx, ky, kz,
                                          raw_w0, raw_g0, raw_b0, raw_w1, raw_g1, raw_b1,
                                          feats);
  conv_sa_kernel<<<2048, 256, 0, stream>>>(cxyz4, vf, kx, ky, kz,
                                           conv_w0, conv_g0, conv_b0, conv_w1, conv_g1, conv_b1,
                                           feats);
  fusion_kernel<<<2048, 256, 0, stream>>>(feats, fus_w, fus_g, fus_b, out);
}